// Round 4
// baseline (273.257 us; speedup 1.0000x reference)
//
#include <hip/hip_runtime.h>

#define NN   10000
#define EE   160000
#define CINC 32
#define COUTC 32
#define RRR  6
#define MMM  3
#define RM   (RRR*MMM)      // 18
#define KK   (RM*CINC)      // 576
#define NPB  4              // nodes per block in k_conv
#define PART_STRIDE 132     // 4*32 + 4 pad (float2 units) per chunk
#define EPSV 1e-8f

// ---------------- prep: zero counts + phased weights (merged) ----------------

__global__ void k_prep(int* __restrict__ counts,
                       const float* __restrict__ w1, const float* __restrict__ off1,
                       const float* __restrict__ w2, const float* __restrict__ off2,
                       float2* __restrict__ Wc1, float2* __restrict__ Wc2) {
    int i = blockIdx.x*blockDim.x + threadIdx.x;
    if (i < NN+1) counts[i] = 0;
    if (i < KK*COUTC) {
        int d = i % COUTC;
        int c = (i / COUTC) % CINC;
        float o1 = off1[c*COUTC + d];
        float o2 = off2[c*COUTC + d];
        float s1 = sinf(o1), c1 = cosf(o1);
        float s2 = sinf(o2), c2 = cosf(o2);
        Wc1[i] = make_float2(w1[i]*c1, w1[i]*s1);
        Wc2[i] = make_float2(w2[i]*c2, w2[i]*s2);
    }
}

__global__ void k_hist(const int* __restrict__ edges, int* __restrict__ counts) {
    int i = blockIdx.x*blockDim.x + threadIdx.x;
    if (i < EE) atomicAdd(&counts[edges[2*i+1]], 1);
}

__global__ void k_scan(int* __restrict__ counts, int* __restrict__ cursor) {
    __shared__ int sums[1024];
    const int CH = 10;                 // 1024*10 >= 10000
    int t = threadIdx.x;
    int beg = t*CH;
    int end = beg + CH; if (end > NN) end = NN;
    int local[CH];
    int s = 0;
    for (int i = beg; i < end; ++i) { int v = counts[i]; local[i-beg] = v; s += v; }
    sums[t] = s;
    __syncthreads();
    for (int off = 1; off < 1024; off <<= 1) {
        int v = 0;
        if (t >= off) v = sums[t-off];
        __syncthreads();
        if (t >= off) sums[t] += v;
        __syncthreads();
    }
    int run = sums[t] - s;             // exclusive prefix
    for (int i = beg; i < end; ++i) { counts[i] = run; cursor[i] = run; run += local[i-beg]; }
    if (t == 1023) counts[NN] = run;   // == EE
}

__global__ void k_scatter(const int* __restrict__ edges, int* __restrict__ cursor,
                          int* __restrict__ srcs, int* __restrict__ eids) {
    int i = blockIdx.x*blockDim.x + threadIdx.x;
    if (i < EE) {
        int src = edges[2*i];
        int tgt = edges[2*i+1];
        int pos = atomicAdd(&cursor[tgt], 1);
        srcs[pos] = src;
        eids[pos] = i;
    }
}

// gather stencil rows into target-sorted order: stens[pos] = stenc[eids[pos]]
// reads: 144B contiguous segments at random bases; writes: fully coalesced.
__global__ void k_reorder(const int* __restrict__ eids,
                          const float4* __restrict__ stenc4,
                          float4* __restrict__ stens4) {
    int i = blockIdx.x*blockDim.x + threadIdx.x;   // EE*9 float4's
    if (i < EE*9) {
        int e = i / 9;
        int comp = i - e*9;
        int eid = eids[e];
        stens4[i] = stenc4[(size_t)eid*9 + comp];
    }
}

// ---------------- fused conv (+optional residual) + tangent nonlin ----------------
// 4 nodes/block, 1 wave per node. Edge phase: lane owns c=l&31 and ALL 18 rm;
// the two 32-lane halves process alternate edges. Stencil is pre-sorted by
// target (k_reorder) so its address is a pure induction variable — rows e,e+1
// are 288B contiguous per wave-iteration. Only src is data-dependent
// (prefetched one iteration ahead).
// Einsum: lane owns a d-pair (float4 Wc loads), 16 chunks x 36 k.

template<bool FINAL>
__global__ void __launch_bounds__(256)
k_conv(const float2* __restrict__ xin,      // (NN,32) complex input
       const int*  __restrict__ offsets,    // (NN+1)
       const int*  __restrict__ srcs,       // (EE) src node, target-sorted
       const float2* __restrict__ stens,    // (EE,18) complex, target-sorted
       const float2* __restrict__ Wc,       // (KK,32) complex
       const float* __restrict__ bias,      // (32)
       const float2* __restrict__ xres,     // (NN,32) original xc (FINAL)
       const float2* __restrict__ resw,     // (32,32) complex (FINAL)
       float2* __restrict__ out)            // (NN,32) complex
{
    __shared__ float2 smem[NPB*KK];         // 18432 B; agg then reused as part
    float2* agg = smem;
    int t = threadIdx.x;

    // ---- edge aggregation ----
    {
        int g = t >> 6;                     // node slot 0..3 (one wave each)
        int l = t & 63;
        int n = blockIdx.x*NPB + g;
        int c = l & 31;
        int h = l >> 5;                     // half: alternate edges
        float2 acc[RM];
        #pragma unroll
        for (int k = 0; k < RM; ++k) acc[k] = make_float2(0.f, 0.f);

        int beg = offsets[n], end = offsets[n+1];
        int e = beg + h;
        const float4* sp = (const float4*)(stens + (size_t)e * RM);
        bool v = (e < end);
        int src = 0;
        if (v) src = srcs[e];
        while (v) {
            int en = e + 2;
            bool vn = (en < end);
            int srcn = 0;
            if (vn) srcn = srcs[en];        // prefetch next src
            float2 xv = xin[(size_t)src * CINC + c];
            #pragma unroll
            for (int j = 0; j < 9; ++j) {
                float4 s = sp[j];
                acc[2*j].x   = fmaf(s.x, xv.x, fmaf(-s.y, xv.y, acc[2*j].x));
                acc[2*j].y   = fmaf(s.x, xv.y, fmaf( s.y, xv.x, acc[2*j].y));
                acc[2*j+1].x = fmaf(s.z, xv.x, fmaf(-s.w, xv.y, acc[2*j+1].x));
                acc[2*j+1].y = fmaf(s.z, xv.y, fmaf( s.w, xv.x, acc[2*j+1].y));
            }
            sp += 18;                       // 2 rows of 9 float4
            e = en; v = vn; src = srcn;
        }
        // merge the two halves (half1 -> half0)
        #pragma unroll
        for (int k = 0; k < RM; ++k) {
            acc[k].x += __shfl_down(acc[k].x, 32, 64);
            acc[k].y += __shfl_down(acc[k].y, 32, 64);
        }
        if (h == 0) {
            #pragma unroll
            for (int k = 0; k < RM; ++k)
                agg[g*KK + k*32 + c] = acc[k];
        }
    }
    __syncthreads();

    // ---- einsum: out[n,d] = sum_k agg[n,k] * Wc[k,d] ----
    int ch = t >> 4;                        // 16 chunks of 36 k's
    int dp = (t & 15) * 2;                  // d-pair base
    int kb = ch * 36;
    float2 p0[NPB], p1[NPB];
    #pragma unroll
    for (int j = 0; j < NPB; ++j) { p0[j] = make_float2(0.f,0.f); p1[j] = make_float2(0.f,0.f); }
    #pragma unroll 4
    for (int q = 0; q < 36; ++q) {
        float4 w = *(const float4*)(Wc + (size_t)(kb + q) * COUTC + dp);
        #pragma unroll
        for (int j = 0; j < NPB; ++j) {
            float2 a = agg[j*KK + kb + q];
            p0[j].x += a.x*w.x - a.y*w.y;
            p0[j].y += a.x*w.y + a.y*w.x;
            p1[j].x += a.x*w.z - a.y*w.w;
            p1[j].y += a.x*w.w + a.y*w.z;
        }
    }
    __syncthreads();                        // all agg reads done; reuse as part
    float2* part = smem;                    // [16][PART_STRIDE] : [ch][j*32+d]
    #pragma unroll
    for (int j = 0; j < NPB; ++j)
        *(float4*)&part[(size_t)ch*PART_STRIDE + j*32 + dp] =
            make_float4(p0[j].x, p0[j].y, p1[j].x, p1[j].y);
    __syncthreads();

    // ---- reduce chunks, residual, nonlinearity ----
    if (t < NPB*32) {
        int j = t >> 5, d = t & 31;
        int n = blockIdx.x*NPB + j;
        float2 hv = make_float2(0.f, 0.f);
        #pragma unroll
        for (int c2 = 0; c2 < 16; ++c2) {
            float2 vv = part[(size_t)c2*PART_STRIDE + j*32 + d];
            hv.x += vv.x; hv.y += vv.y;
        }
        if (FINAL) {
            const float2* xr = xres + (size_t)n * CINC;
            #pragma unroll
            for (int c = 0; c < CINC; ++c) {
                float2 xv = xr[c];
                float2 w = resw[c*COUTC + d];
                hv.x += xv.x*w.x - xv.y*w.y;
                hv.y += xv.x*w.y + xv.y*w.x;
            }
        }
        float mag = sqrtf(hv.x*hv.x + hv.y*hv.y);
        float num = mag + bias[d]; if (num < 0.f) num = 0.f;
        float den = (mag > EPSV) ? mag : EPSV;
        float f = num / den;
        out[(size_t)n*COUTC + d] = make_float2(f*hv.x, f*hv.y);
    }
}

// ---------------- launch ----------------

extern "C" void kernel_launch(void* const* d_in, const int* in_sizes, int n_in,
                              void* d_out, int out_size, void* d_ws, size_t ws_size,
                              hipStream_t stream) {
    const float2* xc   = (const float2*)d_in[0];   // (N,32,2) -> complex
    const int*   edges = (const int*)  d_in[1];    // (E,2)
    const float2* stenc= (const float2*)d_in[2];   // (E,6,3,2) -> (E,18) complex
    const float* w1    = (const float*)d_in[3];
    const float* off1  = (const float*)d_in[4];
    const float* b1    = (const float*)d_in[5];
    const float* w2    = (const float*)d_in[6];
    const float* off2  = (const float*)d_in[7];
    const float* b2    = (const float*)d_in[8];
    const float2* resw = (const float2*)d_in[9];   // (32,32) complex
    float2* out = (float2*)d_out;

    char* ws = (char*)d_ws;
    size_t o = 0;
    auto alloc = [&](size_t bytes) {
        o = (o + 255) & ~(size_t)255;
        size_t r = o; o += bytes; return r;
    };
    int*    counts = (int*)   (ws + alloc((NN+1)*sizeof(int)));
    int*    cursor = (int*)   (ws + alloc(NN*sizeof(int)));
    int*    srcs   = (int*)   (ws + alloc(EE*sizeof(int)));
    int*    eids   = (int*)   (ws + alloc(EE*sizeof(int)));
    float2* stens  = (float2*)(ws + alloc((size_t)EE*RM*sizeof(float2)));
    float2* Wc1    = (float2*)(ws + alloc((size_t)KK*COUTC*sizeof(float2)));
    float2* Wc2    = (float2*)(ws + alloc((size_t)KK*COUTC*sizeof(float2)));
    float2* h      = (float2*)(ws + alloc((size_t)NN*COUTC*sizeof(float2)));
    (void)ws_size; (void)in_sizes; (void)n_in; (void)out_size;

    int prep_n = (KK*COUTC > NN+1) ? KK*COUTC : NN+1;
    k_prep   <<<(prep_n+255)/256, 256, 0, stream>>>(counts, w1, off1, w2, off2, Wc1, Wc2);
    k_hist   <<<(EE+255)/256,   256, 0, stream>>>(edges, counts);
    k_scan   <<<1, 1024, 0, stream>>>(counts, cursor);
    k_scatter<<<(EE+255)/256,   256, 0, stream>>>(edges, cursor, srcs, eids);
    k_reorder<<<(EE*9+255)/256, 256, 0, stream>>>(eids, (const float4*)stenc,
                                                  (float4*)stens);

    k_conv<false><<<NN/NPB, 256, 0, stream>>>(xc, counts, srcs, stens, Wc1, b1,
                                              nullptr, nullptr, h);
    k_conv<true> <<<NN/NPB, 256, 0, stream>>>(h, counts, srcs, stens, Wc2, b2,
                                              xc, resw, out);
}